// Round 3
// baseline (889.655 us; speedup 1.0000x reference)
//
#include <hip/hip_runtime.h>
#include <math.h>

// Problem constants
#define BATCH 128
#define NPER 400
#define EPG 6400
#define NEDGE 819200
#define F_IN 400
#define HD 128
#define K1 320
#define K2 256
#define K3 205

// ---------------- workspace layout ----------------
static constexpr size_t SZ_TREL = 51200ull * 128 * 4;
static constexpr size_t OFF_TREL = 0;
static constexpr size_t OFF_H    = OFF_TREL + SZ_TREL;
static constexpr size_t OFF_HP   = OFF_H + SZ_TREL;
static constexpr size_t OFF_SC   = OFF_HP + 40960ull * 128 * 4;
static constexpr size_t OFF_IDX  = OFF_SC + 51200ull * 4;
static constexpr size_t OFF_VALS = OFF_IDX + 40960ull * 4;
static constexpr size_t OFF_NEWID= OFF_VALS + 40960ull * 4;
static constexpr size_t OFF_ES   = OFF_NEWID + 51200ull * 4;
static constexpr size_t OFF_ED   = OFF_ES + (size_t)NEDGE * 4;
static constexpr size_t OFF_EM   = OFF_ED + (size_t)NEDGE * 4;
static constexpr size_t OFF_Z    = OFF_EM + (size_t)NEDGE * 4;
static constexpr size_t OFF_COFF = OFF_Z + 128ull * 256 * 4;
static constexpr size_t OFF_CDEG = OFF_COFF + 51200ull * 4;
static constexpr size_t OFF_CSRC = OFF_CDEG + 51200ull * 4;
static constexpr size_t OFF_WT1  = OFF_CSRC + (size_t)NEDGE * 4;
static constexpr size_t OFF_WT2  = OFF_WT1 + 400ull * 256 * 4;
static constexpr size_t OFF_WT3  = OFF_WT2 + 128ull * 256 * 4;

// ---------------- weight transpose prep ----------------
// wt[k][n]: n<128 -> Wrel[n][k], n>=128 -> Wroot[n-128][k]
// grid: 400 (L1) + 128 (L2) + 128 (L3) = 656 blocks, 256 threads
__global__ __launch_bounds__(256) void prep_wt(
    const float* __restrict__ Wrel1, const float* __restrict__ Wroot1,
    const float* __restrict__ Wrel2, const float* __restrict__ Wroot2,
    const float* __restrict__ Wrel3, const float* __restrict__ Wroot3,
    float* __restrict__ wt1, float* __restrict__ wt2, float* __restrict__ wt3) {
    int b = blockIdx.x, n = threadIdx.x;
    const float *Wrel, *Wroot; float* wt; int Kd, k;
    if (b < 400)      { Wrel = Wrel1; Wroot = Wroot1; wt = wt1; Kd = 400; k = b; }
    else if (b < 528) { Wrel = Wrel2; Wroot = Wroot2; wt = wt2; Kd = 128; k = b - 400; }
    else              { Wrel = Wrel3; Wroot = Wroot3; wt = wt3; Kd = 128; k = b - 528; }
    wt[k * 256 + n] = (n < 128) ? Wrel[n * Kd + k] : Wroot[(n - 128) * Kd + k];
}

// ---------------- fused GEMM: [t_rel | h] = A @ [Wrel|Wroot]^T ----------------
// A: [M,Kd] row-major. wt: [Kd][256] (pre-transposed, rel|root concatenated).
// Block tile 128(M) x 256(N), thread tile 8x16, block 256 thr, grid M/128.
#define FMA4(c, s, v) { c.x += (s)*(v).x; c.y += (s)*(v).y; c.z += (s)*(v).z; c.w += (s)*(v).w; }
__global__ __launch_bounds__(256, 2) void gemm_fused(
    const float* __restrict__ A, const float* __restrict__ wt,
    float* __restrict__ t_rel, float* __restrict__ h, int Kd) {
    __shared__ float Ast[16][128];  // [k][m]
    __shared__ float Bs[16][256];   // [k][n]
    const int tid = threadIdx.x;
    const int m0 = blockIdx.x * 128;
    const int ty = tid >> 4;        // 0..15 m-group (rows ty*8..+7)
    const int tx = tid & 15;        // 0..15 n-group (cols tx*4 + 64q, q=0..3)
    // staging A: r = tid>>1 (0..127), kq = (tid&1)*8
    const int sr = tid >> 1, skq = (tid & 1) << 3;
    // staging B: bkr = tid>>4 (0..15), bnx = tid&15
    const int bkr = tid >> 4, bnx = tid & 15;

    float4 acc[8][4];
#pragma unroll
    for (int i = 0; i < 8; i++)
#pragma unroll
        for (int q = 0; q < 4; q++) acc[i][q] = make_float4(0.f, 0.f, 0.f, 0.f);

    const float* Arow = A + (size_t)(m0 + sr) * Kd + skq;
    const float* Wrow = wt + (size_t)bkr * 256 + bnx * 4;

    for (int k0 = 0; k0 < Kd; k0 += 16) {
        // stage A (transposed)
        float4 a0 = *(const float4*)&Arow[k0];
        float4 a1 = *(const float4*)&Arow[k0 + 4];
        Ast[skq + 0][sr] = a0.x; Ast[skq + 1][sr] = a0.y;
        Ast[skq + 2][sr] = a0.z; Ast[skq + 3][sr] = a0.w;
        Ast[skq + 4][sr] = a1.x; Ast[skq + 5][sr] = a1.y;
        Ast[skq + 6][sr] = a1.z; Ast[skq + 7][sr] = a1.w;
        // stage B: 4 interleaved float4 chunks per thread
        const float* wr = Wrow + (size_t)k0 * 256;
#pragma unroll
        for (int q = 0; q < 4; q++) {
            float4 b = *(const float4*)&wr[q * 64];
            *(float4*)&Bs[bkr][bnx * 4 + q * 64] = b;
        }
        __syncthreads();
#pragma unroll
        for (int kk = 0; kk < 16; kk++) {
            float4 av0 = *(const float4*)&Ast[kk][ty * 8];
            float4 av1 = *(const float4*)&Ast[kk][ty * 8 + 4];
            float4 bv0 = *(const float4*)&Bs[kk][tx * 4];
            float4 bv1 = *(const float4*)&Bs[kk][64 + tx * 4];
            float4 bv2 = *(const float4*)&Bs[kk][128 + tx * 4];
            float4 bv3 = *(const float4*)&Bs[kk][192 + tx * 4];
            float a[8] = {av0.x, av0.y, av0.z, av0.w, av1.x, av1.y, av1.z, av1.w};
#pragma unroll
            for (int i = 0; i < 8; i++) {
                FMA4(acc[i][0], a[i], bv0);
                FMA4(acc[i][1], a[i], bv1);
                FMA4(acc[i][2], a[i], bv2);
                FMA4(acc[i][3], a[i], bv3);
            }
        }
        __syncthreads();
    }
#pragma unroll
    for (int i = 0; i < 8; i++) {
        size_t row = (size_t)(m0 + ty * 8 + i);
        *(float4*)&t_rel[row * 128 + tx * 4]      = acc[i][0];
        *(float4*)&t_rel[row * 128 + 64 + tx * 4] = acc[i][1];
        *(float4*)&h[row * 128 + tx * 4]          = acc[i][2];
        *(float4*)&h[row * 128 + 64 + tx * 4]     = acc[i][3];
    }
}

// ---------------- CSR build for layer 1 (original edges, no mask) ----------
__global__ __launch_bounds__(1024) void csr_build0(
    const int* __restrict__ gsrc, const int* __restrict__ gdst,
    int* __restrict__ csr_off, int* __restrict__ csr_deg, int* __restrict__ csr_src) {
    __shared__ int cnt[NPER];
    __shared__ int cur[NPER];
    __shared__ int sscan[512];
    const int g = blockIdx.x;
    const int t = threadIdx.x;
    for (int i = t; i < NPER; i += 1024) cnt[i] = 0;
    __syncthreads();
    for (int e = t; e < EPG; e += 1024) {
        int dl = gdst[g * EPG + e] - g * NPER;
        atomicAdd(&cnt[dl], 1);
    }
    __syncthreads();
    if (t < 512) sscan[t] = (t < NPER) ? cnt[t] : 0;
    __syncthreads();
    for (int d = 1; d < 512; d <<= 1) {
        int v = 0;
        if (t < 512 && t >= d) v = sscan[t - d];
        __syncthreads();
        if (t < 512 && t >= d) sscan[t] += v;
        __syncthreads();
    }
    if (t < NPER) {
        int excl = (t == 0) ? 0 : sscan[t - 1];
        int st = g * EPG + excl;
        csr_off[g * NPER + t] = st;
        csr_deg[g * NPER + t] = cnt[t];
        cur[t] = st;
    }
    __syncthreads();
    for (int e = t; e < EPG; e += 1024) {
        int eg = g * EPG + e;
        int dl = gdst[eg] - g * NPER;
        int slot = atomicAdd(&cur[dl], 1);
        csr_src[slot] = gsrc[eg];
    }
}

// ---------------- fused edge remap + CSR build (layers 2,3 conv prep) -------
// Remaps prev-space edges via newid (from topk), writes new es/ed/em and the
// CSR over the new (pooled) node space. One block per graph.
__global__ __launch_bounds__(1024) void csr_remap(
    const int* __restrict__ es_in, const int* __restrict__ ed_in,
    const int* __restrict__ em_in,
    const int* __restrict__ gsrc, const int* __restrict__ gdst,
    const int* __restrict__ newid,
    int* __restrict__ es_out, int* __restrict__ ed_out, int* __restrict__ em_out,
    int* __restrict__ csr_off, int* __restrict__ csr_deg, int* __restrict__ csr_src,
    int npg_prev, int k, int first) {
    __shared__ int nid[NPER];
    __shared__ int packed[EPG];
    __shared__ int cnt[K1];       // k <= 320
    __shared__ int cur[K1];
    __shared__ int sscan[512];
    const int g = blockIdx.x;
    const int t = threadIdx.x;
    for (int i = t; i < npg_prev; i += 1024) nid[i] = newid[g * npg_prev + i];
    for (int i = t; i < k; i += 1024) cnt[i] = 0;
    __syncthreads();
    for (int e = t; e < EPG; e += 1024) {
        int eg = g * EPG + e;
        int sl, dl, m;
        if (first) { sl = gsrc[eg] - g * NPER; dl = gdst[eg] - g * NPER; m = 1; }
        else       { sl = es_in[eg]; dl = ed_in[eg]; m = em_in[eg]; }
        int ns = nid[sl], nd = nid[dl];
        int keep = (m && ns >= 0 && nd >= 0) ? 1 : 0;
        es_out[eg] = keep ? ns : 0;
        ed_out[eg] = keep ? nd : 0;
        em_out[eg] = keep;
        packed[e] = keep ? (ns | (nd << 16)) : -1;
        if (keep) atomicAdd(&cnt[nd], 1);
    }
    __syncthreads();
    if (t < 512) sscan[t] = (t < k) ? cnt[t] : 0;
    __syncthreads();
    for (int d = 1; d < 512; d <<= 1) {
        int v = 0;
        if (t < 512 && t >= d) v = sscan[t - d];
        __syncthreads();
        if (t < 512 && t >= d) sscan[t] += v;
        __syncthreads();
    }
    if (t < k) {
        int excl = (t == 0) ? 0 : sscan[t - 1];
        int st = g * EPG + excl;
        csr_off[g * k + t] = st;
        csr_deg[g * k + t] = cnt[t];
        cur[t] = st;
    }
    __syncthreads();
    for (int e = t; e < EPG; e += 1024) {
        int p = packed[e];
        if (p >= 0) {
            int ns = p & 0xffff, nd = p >> 16;
            int slot = atomicAdd(&cur[nd], 1);
            csr_src[slot] = g * k + ns;
        }
    }
}

// ---------------- Aggregation (gather) + combine + relu + score ------------
// One wave per destination node; lane covers features {2*lane, 2*lane+1}.
__global__ __launch_bounds__(256) void agg_score(
    const float* __restrict__ t_rel,
    const int* __restrict__ csr_off, const int* __restrict__ csr_deg,
    const int* __restrict__ csr_src,
    const float* __restrict__ bias, const float* __restrict__ pw,
    float* __restrict__ h, float* __restrict__ sc, int total_nodes) {
    const int wid = (blockIdx.x * 256 + threadIdx.x) >> 6;
    const int lane = threadIdx.x & 63;
    if (wid >= total_nodes) return;
    const int start = csr_off[wid];
    const int deg = csr_deg[wid];
    float a0 = 0.f, a1 = 0.f;
    for (int e = 0; e < deg; e++) {
        int srow = csr_src[start + e];
        float2 v = *(const float2*)&t_rel[(size_t)srow * 128 + lane * 2];
        a0 += v.x; a1 += v.y;
    }
    float2 bb = *(const float2*)&bias[lane * 2];
    size_t o = (size_t)wid * 128 + lane * 2;
    float2 hv = *(const float2*)&h[o];
    hv.x = fmaxf(hv.x + a0 + bb.x, 0.f);
    hv.y = fmaxf(hv.y + a1 + bb.y, 0.f);
    *(float2*)&h[o] = hv;
    float2 pp = *(const float2*)&pw[lane * 2];
    float d = hv.x * pp.x + hv.y * pp.y;
    float nr = pp.x * pp.x + pp.y * pp.y;
#pragma unroll
    for (int off = 32; off; off >>= 1) {
        d += __shfl_down(d, off, 64);
        nr += __shfl_down(nr, off, 64);
    }
    if (lane == 0) sc[wid] = d / (sqrtf(nr) + 1e-16f);
}

// ---------------- topk per graph: exact bitonic sort of 512 ----------------
__device__ __forceinline__ bool rank_before(float as, int ai, float bs, int bi) {
    return (as > bs) || (as == bs && ai < bi);
}
__global__ __launch_bounds__(256) void topk_kernel(const float* __restrict__ sc,
                                                   int* __restrict__ idxo,
                                                   float* __restrict__ valso,
                                                   int* __restrict__ newid,
                                                   int npg, int k) {
    __shared__ float sk[512];
    __shared__ int si[512];
    const int g = blockIdx.x;
    for (int t = threadIdx.x; t < 512; t += 256) {
        sk[t] = (t < npg) ? sc[g * npg + t] : -INFINITY;
        si[t] = t;
    }
    __syncthreads();
    for (int size = 2; size <= 512; size <<= 1) {
        for (int stride = size >> 1; stride; stride >>= 1) {
            for (int i = threadIdx.x; i < 512; i += 256) {
                int j = i ^ stride;
                if (j > i) {
                    bool up = ((i & size) == 0);
                    float a = sk[i], b = sk[j];
                    int ai = si[i], bi = si[j];
                    bool doswap = up ? rank_before(b, bi, a, ai)
                                     : rank_before(a, ai, b, bi);
                    if (doswap) { sk[i] = b; sk[j] = a; si[i] = bi; si[j] = ai; }
                }
            }
            __syncthreads();
        }
    }
    for (int t = threadIdx.x; t < 512; t += 256) {
        if (t < npg) {
            int orig = si[t];
            newid[g * npg + orig] = (t < k) ? t : -1;
            if (t < k) { idxo[g * k + t] = orig; valso[g * k + t] = sk[t]; }
        }
    }
}

// ---------------- fused gather+gate+(hp write)+readout ----------------
// grid = BATCH, block = 128. hp may be null (layer 3: readout only).
__global__ __launch_bounds__(128) void pool_readout(
    const float* __restrict__ h, const int* __restrict__ idx,
    const float* __restrict__ vals, float* __restrict__ hp,
    float* __restrict__ z, int npg, int k) {
    __shared__ float tg[K1];   // k <= 320
    __shared__ int ix[K1];
    const int g = blockIdx.x, f = threadIdx.x;
    for (int j = f; j < k; j += 128) {
        tg[j] = tanhf(vals[g * k + j]);
        ix[j] = idx[g * k + j];
    }
    __syncthreads();
    float mx = -INFINITY, sm = 0.f;
    for (int j = 0; j < k; j++) {
        float v = h[(size_t)(g * npg + ix[j]) * 128 + f] * tg[j];
        if (hp) hp[(size_t)(g * k + j) * 128 + f] = v;
        mx = fmaxf(mx, v);
        sm += v;
    }
    z[g * 256 + f] += mx;
    z[g * 256 + 128 + f] += sm / (float)k;
}

// ---------------- MLP head + log_softmax ----------------
__global__ __launch_bounds__(256) void mlp_head(const float* __restrict__ z,
                                                const float* __restrict__ W1,
                                                const float* __restrict__ bl1,
                                                const float* __restrict__ W2,
                                                const float* __restrict__ bl2,
                                                const float* __restrict__ W3,
                                                const float* __restrict__ bl3,
                                                float* __restrict__ out) {
    __shared__ float zs[256], l1[128], l2[64];
    const int g = blockIdx.x, t = threadIdx.x;
    zs[t] = z[g * 256 + t];
    __syncthreads();
    if (t < 128) {
        float s = bl1[t];
        const float* w = &W1[t * 256];
        for (int i = 0; i < 256; i++) s += w[i] * zs[i];
        l1[t] = fmaxf(s, 0.f);
    }
    __syncthreads();
    if (t < 64) {
        float s = bl2[t];
        const float* w = &W2[t * 128];
        for (int i = 0; i < 128; i++) s += w[i] * l1[i];
        l2[t] = fmaxf(s, 0.f);
    }
    __syncthreads();
    if (t == 0) {
        float a = bl3[0], b = bl3[1];
        for (int i = 0; i < 64; i++) { a += W3[i] * l2[i]; b += W3[64 + i] * l2[i]; }
        float m = fmaxf(a, b);
        float lse = m + logf(expf(a - m) + expf(b - m));
        out[g * 2 + 0] = a - lse;
        out[g * 2 + 1] = b - lse;
    }
}

// ---------------- launch ----------------
extern "C" void kernel_launch(void* const* d_in, const int* in_sizes, int n_in,
                              void* d_out, int out_size, void* d_ws, size_t ws_size,
                              hipStream_t stream) {
    const float* x        = (const float*)d_in[0];
    const int*   edge_src = (const int*)d_in[1];
    const int*   edge_dst = (const int*)d_in[2];
    const float* Wrel1 = (const float*)d_in[4];
    const float* Wroot1= (const float*)d_in[5];
    const float* b1    = (const float*)d_in[6];
    const float* pw1   = (const float*)d_in[7];
    const float* Wrel2 = (const float*)d_in[8];
    const float* Wroot2= (const float*)d_in[9];
    const float* b2    = (const float*)d_in[10];
    const float* pw2   = (const float*)d_in[11];
    const float* Wrel3 = (const float*)d_in[12];
    const float* Wroot3= (const float*)d_in[13];
    const float* b3    = (const float*)d_in[14];
    const float* pw3   = (const float*)d_in[15];
    const float* W1    = (const float*)d_in[16];
    const float* bl1   = (const float*)d_in[17];
    const float* W2    = (const float*)d_in[18];
    const float* bl2   = (const float*)d_in[19];
    const float* W3    = (const float*)d_in[20];
    const float* bl3   = (const float*)d_in[21];

    char* ws = (char*)d_ws;
    float* t_rel = (float*)(ws + OFF_TREL);
    float* h     = (float*)(ws + OFF_H);
    float* hp    = (float*)(ws + OFF_HP);
    float* sc    = (float*)(ws + OFF_SC);
    int*   idx   = (int*)(ws + OFF_IDX);
    float* vals  = (float*)(ws + OFF_VALS);
    int*   newid = (int*)(ws + OFF_NEWID);
    int*   es    = (int*)(ws + OFF_ES);
    int*   ed    = (int*)(ws + OFF_ED);
    int*   em    = (int*)(ws + OFF_EM);
    float* z     = (float*)(ws + OFF_Z);
    int*   coff  = (int*)(ws + OFF_COFF);
    int*   cdeg  = (int*)(ws + OFF_CDEG);
    int*   csrc  = (int*)(ws + OFF_CSRC);
    float* wt1   = (float*)(ws + OFF_WT1);
    float* wt2   = (float*)(ws + OFF_WT2);
    float* wt3   = (float*)(ws + OFF_WT3);

    hipMemsetAsync(z, 0, 128ull * 256 * 4, stream);
    prep_wt<<<656, 256, 0, stream>>>(Wrel1, Wroot1, Wrel2, Wroot2, Wrel3, Wroot3,
                                     wt1, wt2, wt3);
    csr_build0<<<BATCH, 1024, 0, stream>>>(edge_src, edge_dst, coff, cdeg, csrc);

    // ---------- layer 1 ----------
    gemm_fused<<<400, 256, 0, stream>>>(x, wt1, t_rel, h, F_IN);
    agg_score<<<51200 / 4, 256, 0, stream>>>(t_rel, coff, cdeg, csrc, b1, pw1,
                                             h, sc, 51200);
    topk_kernel<<<BATCH, 256, 0, stream>>>(sc, idx, vals, newid, NPER, K1);
    csr_remap<<<BATCH, 1024, 0, stream>>>(nullptr, nullptr, nullptr,
                                          edge_src, edge_dst, newid,
                                          es, ed, em, coff, cdeg, csrc,
                                          NPER, K1, 1);
    pool_readout<<<BATCH, 128, 0, stream>>>(h, idx, vals, hp, z, NPER, K1);

    // ---------- layer 2 ----------
    gemm_fused<<<320, 256, 0, stream>>>(hp, wt2, t_rel, h, HD);
    agg_score<<<40960 / 4, 256, 0, stream>>>(t_rel, coff, cdeg, csrc, b2, pw2,
                                             h, sc, 40960);
    topk_kernel<<<BATCH, 256, 0, stream>>>(sc, idx, vals, newid, K1, K2);
    csr_remap<<<BATCH, 1024, 0, stream>>>(es, ed, em, nullptr, nullptr, newid,
                                          es, ed, em, coff, cdeg, csrc,
                                          K1, K2, 0);
    pool_readout<<<BATCH, 128, 0, stream>>>(h, idx, vals, hp, z, K1, K2);

    // ---------- layer 3 ----------
    gemm_fused<<<256, 256, 0, stream>>>(hp, wt3, t_rel, h, HD);
    agg_score<<<32768 / 4, 256, 0, stream>>>(t_rel, coff, cdeg, csrc, b3, pw3,
                                             h, sc, 32768);
    topk_kernel<<<BATCH, 256, 0, stream>>>(sc, idx, vals, newid, K2, K3);
    pool_readout<<<BATCH, 128, 0, stream>>>(h, idx, vals, nullptr, z, K2, K3);

    // ---------- MLP head ----------
    mlp_head<<<BATCH, 256, 0, stream>>>(z, W1, bl1, W2, bl2, W3, bl3, (float*)d_out);
}

// Round 4
// 745.059 us; speedup vs baseline: 1.1941x; 1.1941x over previous
//
#include <hip/hip_runtime.h>
#include <math.h>

// Problem constants
#define BATCH 128
#define NPER 400
#define EPG 6400
#define NEDGE 819200
#define F_IN 400
#define HD 128
#define K1 320
#define K2 256
#define K3 205

// ---------------- workspace layout ----------------
static constexpr size_t SZ_TREL = 51200ull * 128 * 4;
static constexpr size_t OFF_TREL = 0;
static constexpr size_t OFF_H    = OFF_TREL + SZ_TREL;
static constexpr size_t OFF_HP   = OFF_H + SZ_TREL;
static constexpr size_t OFF_SC   = OFF_HP + 40960ull * 128 * 4;
static constexpr size_t OFF_IDX  = OFF_SC + 51200ull * 4;
static constexpr size_t OFF_VALS = OFF_IDX + 40960ull * 4;
static constexpr size_t OFF_NEWID= OFF_VALS + 40960ull * 4;
static constexpr size_t OFF_ES   = OFF_NEWID + 51200ull * 4;
static constexpr size_t OFF_ED   = OFF_ES + (size_t)NEDGE * 4;
static constexpr size_t OFF_EM   = OFF_ED + (size_t)NEDGE * 4;
static constexpr size_t OFF_Z    = OFF_EM + (size_t)NEDGE * 4;
static constexpr size_t OFF_COFF = OFF_Z + 128ull * 256 * 4;
static constexpr size_t OFF_CDEG = OFF_COFF + 51200ull * 4;
static constexpr size_t OFF_CSRC = OFF_CDEG + 51200ull * 4;
static constexpr size_t OFF_WT1  = OFF_CSRC + (size_t)NEDGE * 4;
static constexpr size_t OFF_WT2  = OFF_WT1 + 400ull * 256 * 4;
static constexpr size_t OFF_WT3  = OFF_WT2 + 128ull * 256 * 4;

// ---------------- weight transpose prep ----------------
// wt[k][n]: n<128 -> Wrel[n][k], n>=128 -> Wroot[n-128][k]
__global__ __launch_bounds__(256) void prep_wt(
    const float* __restrict__ Wrel1, const float* __restrict__ Wroot1,
    const float* __restrict__ Wrel2, const float* __restrict__ Wroot2,
    const float* __restrict__ Wrel3, const float* __restrict__ Wroot3,
    float* __restrict__ wt1, float* __restrict__ wt2, float* __restrict__ wt3) {
    int b = blockIdx.x, n = threadIdx.x;
    const float *Wrel, *Wroot; float* wt; int Kd, k;
    if (b < 400)      { Wrel = Wrel1; Wroot = Wroot1; wt = wt1; Kd = 400; k = b; }
    else if (b < 528) { Wrel = Wrel2; Wroot = Wroot2; wt = wt2; Kd = 128; k = b - 400; }
    else              { Wrel = Wrel3; Wroot = Wroot3; wt = wt3; Kd = 128; k = b - 528; }
    wt[k * 256 + n] = (n < 128) ? Wrel[n * Kd + k] : Wroot[(n - 128) * Kd + k];
}

// ---------------- fused GEMM: [t_rel | h] = A @ [Wrel|Wroot]^T ----------------
// A: [M,Kd] row-major. wt: [Kd][256] (pre-transposed, rel|root side by side).
// Block tile 64(M) x 256(N), thread tile 8x16, block = 128 threads (2 waves).
// Grid = M/64 (800/640/512 blocks -> ~3 blocks/CU for latency hiding).
// Bs padded to 260 floats/row: staging writes land <=2-way per bank (free).
#define FMA4(c, s, v) { c.x += (s)*(v).x; c.y += (s)*(v).y; c.z += (s)*(v).z; c.w += (s)*(v).w; }
__global__ __launch_bounds__(128) void gemm_fused(
    const float* __restrict__ A, const float* __restrict__ wt,
    float* __restrict__ t_rel, float* __restrict__ h, int Kd) {
    __shared__ float Ast[16][64];    // [k][m] 4 KB
    __shared__ float Bs[16][260];    // [k][n] padded, 16.6 KB
    const int tid = threadIdx.x;
    const int m0 = blockIdx.x * 64;
    const int ty = tid >> 4;         // 0..7  (rows ty*8 .. +7)
    const int tx = tid & 15;         // 0..15 (cols tx*4 + 64q)
    const int sr = tid >> 1, skq = (tid & 1) << 3;   // A staging
    const int bkr = tid >> 4, bnx = tid & 15;        // B staging (rows bkr, bkr+8)

    float4 acc[8][4];
#pragma unroll
    for (int i = 0; i < 8; i++)
#pragma unroll
        for (int q = 0; q < 4; q++) acc[i][q] = make_float4(0.f, 0.f, 0.f, 0.f);

    const float* Arow = A + (size_t)(m0 + sr) * Kd + skq;
    const float* Wrow0 = wt + (size_t)bkr * 256 + bnx * 4;
    const float* Wrow1 = wt + (size_t)(bkr + 8) * 256 + bnx * 4;

    for (int k0 = 0; k0 < Kd; k0 += 16) {
        // stage A (transposed)
        float4 a0 = *(const float4*)&Arow[k0];
        float4 a1 = *(const float4*)&Arow[k0 + 4];
        Ast[skq + 0][sr] = a0.x; Ast[skq + 1][sr] = a0.y;
        Ast[skq + 2][sr] = a0.z; Ast[skq + 3][sr] = a0.w;
        Ast[skq + 4][sr] = a1.x; Ast[skq + 5][sr] = a1.y;
        Ast[skq + 6][sr] = a1.z; Ast[skq + 7][sr] = a1.w;
        // stage B: 2 rows x 4 interleaved float4 chunks per thread
        const float* w0 = Wrow0 + (size_t)k0 * 256;
        const float* w1 = Wrow1 + (size_t)k0 * 256;
#pragma unroll
        for (int q = 0; q < 4; q++) {
            float4 b0 = *(const float4*)&w0[q * 64];
            float4 b1 = *(const float4*)&w1[q * 64];
            *(float4*)&Bs[bkr][bnx * 4 + q * 64] = b0;
            *(float4*)&Bs[bkr + 8][bnx * 4 + q * 64] = b1;
        }
        __syncthreads();
#pragma unroll
        for (int kk = 0; kk < 16; kk++) {
            float4 av0 = *(const float4*)&Ast[kk][ty * 8];
            float4 av1 = *(const float4*)&Ast[kk][ty * 8 + 4];
            float4 bv0 = *(const float4*)&Bs[kk][tx * 4];
            float4 bv1 = *(const float4*)&Bs[kk][64 + tx * 4];
            float4 bv2 = *(const float4*)&Bs[kk][128 + tx * 4];
            float4 bv3 = *(const float4*)&Bs[kk][192 + tx * 4];
            float a[8] = {av0.x, av0.y, av0.z, av0.w, av1.x, av1.y, av1.z, av1.w};
#pragma unroll
            for (int i = 0; i < 8; i++) {
                FMA4(acc[i][0], a[i], bv0);
                FMA4(acc[i][1], a[i], bv1);
                FMA4(acc[i][2], a[i], bv2);
                FMA4(acc[i][3], a[i], bv3);
            }
        }
        __syncthreads();
    }
#pragma unroll
    for (int i = 0; i < 8; i++) {
        size_t row = (size_t)(m0 + ty * 8 + i);
        *(float4*)&t_rel[row * 128 + tx * 4]      = acc[i][0];
        *(float4*)&t_rel[row * 128 + 64 + tx * 4] = acc[i][1];
        *(float4*)&h[row * 128 + tx * 4]          = acc[i][2];
        *(float4*)&h[row * 128 + 64 + tx * 4]     = acc[i][3];
    }
}

// ---------------- CSR build for layer 1 (original edges, no mask) ----------
__global__ __launch_bounds__(1024) void csr_build0(
    const int* __restrict__ gsrc, const int* __restrict__ gdst,
    int* __restrict__ csr_off, int* __restrict__ csr_deg, int* __restrict__ csr_src) {
    __shared__ int cnt[NPER];
    __shared__ int cur[NPER];
    __shared__ int sscan[512];
    const int g = blockIdx.x;
    const int t = threadIdx.x;
    for (int i = t; i < NPER; i += 1024) cnt[i] = 0;
    __syncthreads();
    for (int e = t; e < EPG; e += 1024) {
        int dl = gdst[g * EPG + e] - g * NPER;
        atomicAdd(&cnt[dl], 1);
    }
    __syncthreads();
    if (t < 512) sscan[t] = (t < NPER) ? cnt[t] : 0;
    __syncthreads();
    for (int d = 1; d < 512; d <<= 1) {
        int v = 0;
        if (t < 512 && t >= d) v = sscan[t - d];
        __syncthreads();
        if (t < 512 && t >= d) sscan[t] += v;
        __syncthreads();
    }
    if (t < NPER) {
        int excl = (t == 0) ? 0 : sscan[t - 1];
        int st = g * EPG + excl;
        csr_off[g * NPER + t] = st;
        csr_deg[g * NPER + t] = cnt[t];
        cur[t] = st;
    }
    __syncthreads();
    for (int e = t; e < EPG; e += 1024) {
        int eg = g * EPG + e;
        int dl = gdst[eg] - g * NPER;
        int slot = atomicAdd(&cur[dl], 1);
        csr_src[slot] = gsrc[eg];
    }
}

// ---------------- fused edge remap + CSR build (layers 2,3 conv prep) -------
__global__ __launch_bounds__(1024) void csr_remap(
    const int* __restrict__ es_in, const int* __restrict__ ed_in,
    const int* __restrict__ em_in,
    const int* __restrict__ gsrc, const int* __restrict__ gdst,
    const int* __restrict__ newid,
    int* __restrict__ es_out, int* __restrict__ ed_out, int* __restrict__ em_out,
    int* __restrict__ csr_off, int* __restrict__ csr_deg, int* __restrict__ csr_src,
    int npg_prev, int k, int first) {
    __shared__ int nid[NPER];
    __shared__ int packed[EPG];
    __shared__ int cnt[K1];
    __shared__ int cur[K1];
    __shared__ int sscan[512];
    const int g = blockIdx.x;
    const int t = threadIdx.x;
    for (int i = t; i < npg_prev; i += 1024) nid[i] = newid[g * npg_prev + i];
    for (int i = t; i < k; i += 1024) cnt[i] = 0;
    __syncthreads();
    for (int e = t; e < EPG; e += 1024) {
        int eg = g * EPG + e;
        int sl, dl, m;
        if (first) { sl = gsrc[eg] - g * NPER; dl = gdst[eg] - g * NPER; m = 1; }
        else       { sl = es_in[eg]; dl = ed_in[eg]; m = em_in[eg]; }
        int ns = nid[sl], nd = nid[dl];
        int keep = (m && ns >= 0 && nd >= 0) ? 1 : 0;
        es_out[eg] = keep ? ns : 0;
        ed_out[eg] = keep ? nd : 0;
        em_out[eg] = keep;
        packed[e] = keep ? (ns | (nd << 16)) : -1;
        if (keep) atomicAdd(&cnt[nd], 1);
    }
    __syncthreads();
    if (t < 512) sscan[t] = (t < k) ? cnt[t] : 0;
    __syncthreads();
    for (int d = 1; d < 512; d <<= 1) {
        int v = 0;
        if (t < 512 && t >= d) v = sscan[t - d];
        __syncthreads();
        if (t < 512 && t >= d) sscan[t] += v;
        __syncthreads();
    }
    if (t < k) {
        int excl = (t == 0) ? 0 : sscan[t - 1];
        int st = g * EPG + excl;
        csr_off[g * k + t] = st;
        csr_deg[g * k + t] = cnt[t];
        cur[t] = st;
    }
    __syncthreads();
    for (int e = t; e < EPG; e += 1024) {
        int p = packed[e];
        if (p >= 0) {
            int ns = p & 0xffff, nd = p >> 16;
            int slot = atomicAdd(&cur[nd], 1);
            csr_src[slot] = g * k + ns;
        }
    }
}

// ---------------- Aggregation (gather) + combine + relu + score ------------
__global__ __launch_bounds__(256) void agg_score(
    const float* __restrict__ t_rel,
    const int* __restrict__ csr_off, const int* __restrict__ csr_deg,
    const int* __restrict__ csr_src,
    const float* __restrict__ bias, const float* __restrict__ pw,
    float* __restrict__ h, float* __restrict__ sc, int total_nodes) {
    const int wid = (blockIdx.x * 256 + threadIdx.x) >> 6;
    const int lane = threadIdx.x & 63;
    if (wid >= total_nodes) return;
    const int start = csr_off[wid];
    const int deg = csr_deg[wid];
    float a0 = 0.f, a1 = 0.f;
    for (int e = 0; e < deg; e++) {
        int srow = csr_src[start + e];
        float2 v = *(const float2*)&t_rel[(size_t)srow * 128 + lane * 2];
        a0 += v.x; a1 += v.y;
    }
    float2 bb = *(const float2*)&bias[lane * 2];
    size_t o = (size_t)wid * 128 + lane * 2;
    float2 hv = *(const float2*)&h[o];
    hv.x = fmaxf(hv.x + a0 + bb.x, 0.f);
    hv.y = fmaxf(hv.y + a1 + bb.y, 0.f);
    *(float2*)&h[o] = hv;
    float2 pp = *(const float2*)&pw[lane * 2];
    float d = hv.x * pp.x + hv.y * pp.y;
    float nr = pp.x * pp.x + pp.y * pp.y;
#pragma unroll
    for (int off = 32; off; off >>= 1) {
        d += __shfl_down(d, off, 64);
        nr += __shfl_down(nr, off, 64);
    }
    if (lane == 0) sc[wid] = d / (sqrtf(nr) + 1e-16f);
}

// ---------------- topk per graph: exact bitonic sort of 512 ----------------
__device__ __forceinline__ bool rank_before(float as, int ai, float bs, int bi) {
    return (as > bs) || (as == bs && ai < bi);
}
__global__ __launch_bounds__(256) void topk_kernel(const float* __restrict__ sc,
                                                   int* __restrict__ idxo,
                                                   float* __restrict__ valso,
                                                   int* __restrict__ newid,
                                                   int npg, int k) {
    __shared__ float sk[512];
    __shared__ int si[512];
    const int g = blockIdx.x;
    for (int t = threadIdx.x; t < 512; t += 256) {
        sk[t] = (t < npg) ? sc[g * npg + t] : -INFINITY;
        si[t] = t;
    }
    __syncthreads();
    for (int size = 2; size <= 512; size <<= 1) {
        for (int stride = size >> 1; stride; stride >>= 1) {
            for (int i = threadIdx.x; i < 512; i += 256) {
                int j = i ^ stride;
                if (j > i) {
                    bool up = ((i & size) == 0);
                    float a = sk[i], b = sk[j];
                    int ai = si[i], bi = si[j];
                    bool doswap = up ? rank_before(b, bi, a, ai)
                                     : rank_before(a, ai, b, bi);
                    if (doswap) { sk[i] = b; sk[j] = a; si[i] = bi; si[j] = ai; }
                }
            }
            __syncthreads();
        }
    }
    for (int t = threadIdx.x; t < 512; t += 256) {
        if (t < npg) {
            int orig = si[t];
            newid[g * npg + orig] = (t < k) ? t : -1;
            if (t < k) { idxo[g * k + t] = orig; valso[g * k + t] = sk[t]; }
        }
    }
}

// ---------------- fused gather+gate+(hp write)+readout ----------------
// grid = BATCH, block = 512 (4-way parallel over j). hp may be null (layer 3).
__global__ __launch_bounds__(512) void pool_readout(
    const float* __restrict__ h, const int* __restrict__ idx,
    const float* __restrict__ vals, float* __restrict__ hp,
    float* __restrict__ z, int npg, int k) {
    __shared__ float tg[K1];
    __shared__ int ix[K1];
    __shared__ float pmx[4][128], psm[4][128];
    const int g = blockIdx.x;
    const int f = threadIdx.x & 127;
    const int jq = threadIdx.x >> 7;      // 0..3
    for (int j = threadIdx.x; j < k; j += 512) {
        tg[j] = tanhf(vals[g * k + j]);
        ix[j] = idx[g * k + j];
    }
    __syncthreads();
    float mx = -INFINITY, sm = 0.f;
    for (int j = jq; j < k; j += 4) {
        float v = h[(size_t)(g * npg + ix[j]) * 128 + f] * tg[j];
        if (hp) hp[(size_t)(g * k + j) * 128 + f] = v;
        mx = fmaxf(mx, v);
        sm += v;
    }
    pmx[jq][f] = mx; psm[jq][f] = sm;
    __syncthreads();
    if (threadIdx.x < 128) {
        mx = fmaxf(fmaxf(pmx[0][f], pmx[1][f]), fmaxf(pmx[2][f], pmx[3][f]));
        sm = psm[0][f] + psm[1][f] + psm[2][f] + psm[3][f];
        z[g * 256 + f] += mx;
        z[g * 256 + 128 + f] += sm / (float)k;
    }
}

// ---------------- MLP head + log_softmax ----------------
__global__ __launch_bounds__(256) void mlp_head(const float* __restrict__ z,
                                                const float* __restrict__ W1,
                                                const float* __restrict__ bl1,
                                                const float* __restrict__ W2,
                                                const float* __restrict__ bl2,
                                                const float* __restrict__ W3,
                                                const float* __restrict__ bl3,
                                                float* __restrict__ out) {
    __shared__ float zs[256], l1[128], l2[64];
    const int g = blockIdx.x, t = threadIdx.x;
    zs[t] = z[g * 256 + t];
    __syncthreads();
    if (t < 128) {
        float s = bl1[t];
        const float* w = &W1[t * 256];
        for (int i = 0; i < 256; i++) s += w[i] * zs[i];
        l1[t] = fmaxf(s, 0.f);
    }
    __syncthreads();
    if (t < 64) {
        float s = bl2[t];
        const float* w = &W2[t * 128];
        for (int i = 0; i < 128; i++) s += w[i] * l1[i];
        l2[t] = fmaxf(s, 0.f);
    }
    __syncthreads();
    if (t == 0) {
        float a = bl3[0], b = bl3[1];
        for (int i = 0; i < 64; i++) { a += W3[i] * l2[i]; b += W3[64 + i] * l2[i]; }
        float m = fmaxf(a, b);
        float lse = m + logf(expf(a - m) + expf(b - m));
        out[g * 2 + 0] = a - lse;
        out[g * 2 + 1] = b - lse;
    }
}

// ---------------- launch ----------------
extern "C" void kernel_launch(void* const* d_in, const int* in_sizes, int n_in,
                              void* d_out, int out_size, void* d_ws, size_t ws_size,
                              hipStream_t stream) {
    const float* x        = (const float*)d_in[0];
    const int*   edge_src = (const int*)d_in[1];
    const int*   edge_dst = (const int*)d_in[2];
    const float* Wrel1 = (const float*)d_in[4];
    const float* Wroot1= (const float*)d_in[5];
    const float* b1    = (const float*)d_in[6];
    const float* pw1   = (const float*)d_in[7];
    const float* Wrel2 = (const float*)d_in[8];
    const float* Wroot2= (const float*)d_in[9];
    const float* b2    = (const float*)d_in[10];
    const float* pw2   = (const float*)d_in[11];
    const float* Wrel3 = (const float*)d_in[12];
    const float* Wroot3= (const float*)d_in[13];
    const float* b3    = (const float*)d_in[14];
    const float* pw3   = (const float*)d_in[15];
    const float* W1    = (const float*)d_in[16];
    const float* bl1   = (const float*)d_in[17];
    const float* W2    = (const float*)d_in[18];
    const float* bl2   = (const float*)d_in[19];
    const float* W3    = (const float*)d_in[20];
    const float* bl3   = (const float*)d_in[21];

    char* ws = (char*)d_ws;
    float* t_rel = (float*)(ws + OFF_TREL);
    float* h     = (float*)(ws + OFF_H);
    float* hp    = (float*)(ws + OFF_HP);
    float* sc    = (float*)(ws + OFF_SC);
    int*   idx   = (int*)(ws + OFF_IDX);
    float* vals  = (float*)(ws + OFF_VALS);
    int*   newid = (int*)(ws + OFF_NEWID);
    int*   es    = (int*)(ws + OFF_ES);
    int*   ed    = (int*)(ws + OFF_ED);
    int*   em    = (int*)(ws + OFF_EM);
    float* z     = (float*)(ws + OFF_Z);
    int*   coff  = (int*)(ws + OFF_COFF);
    int*   cdeg  = (int*)(ws + OFF_CDEG);
    int*   csrc  = (int*)(ws + OFF_CSRC);
    float* wt1   = (float*)(ws + OFF_WT1);
    float* wt2   = (float*)(ws + OFF_WT2);
    float* wt3   = (float*)(ws + OFF_WT3);

    hipMemsetAsync(z, 0, 128ull * 256 * 4, stream);
    prep_wt<<<656, 256, 0, stream>>>(Wrel1, Wroot1, Wrel2, Wroot2, Wrel3, Wroot3,
                                     wt1, wt2, wt3);
    csr_build0<<<BATCH, 1024, 0, stream>>>(edge_src, edge_dst, coff, cdeg, csrc);

    // ---------- layer 1 ----------
    gemm_fused<<<800, 128, 0, stream>>>(x, wt1, t_rel, h, F_IN);
    agg_score<<<51200 / 4, 256, 0, stream>>>(t_rel, coff, cdeg, csrc, b1, pw1,
                                             h, sc, 51200);
    topk_kernel<<<BATCH, 256, 0, stream>>>(sc, idx, vals, newid, NPER, K1);
    csr_remap<<<BATCH, 1024, 0, stream>>>(nullptr, nullptr, nullptr,
                                          edge_src, edge_dst, newid,
                                          es, ed, em, coff, cdeg, csrc,
                                          NPER, K1, 1);
    pool_readout<<<BATCH, 512, 0, stream>>>(h, idx, vals, hp, z, NPER, K1);

    // ---------- layer 2 ----------
    gemm_fused<<<640, 128, 0, stream>>>(hp, wt2, t_rel, h, HD);
    agg_score<<<40960 / 4, 256, 0, stream>>>(t_rel, coff, cdeg, csrc, b2, pw2,
                                             h, sc, 40960);
    topk_kernel<<<BATCH, 256, 0, stream>>>(sc, idx, vals, newid, K1, K2);
    csr_remap<<<BATCH, 1024, 0, stream>>>(es, ed, em, nullptr, nullptr, newid,
                                          es, ed, em, coff, cdeg, csrc,
                                          K1, K2, 0);
    pool_readout<<<BATCH, 512, 0, stream>>>(h, idx, vals, hp, z, K1, K2);

    // ---------- layer 3 ----------
    gemm_fused<<<512, 128, 0, stream>>>(hp, wt3, t_rel, h, HD);
    agg_score<<<32768 / 4, 256, 0, stream>>>(t_rel, coff, cdeg, csrc, b3, pw3,
                                             h, sc, 32768);
    topk_kernel<<<BATCH, 256, 0, stream>>>(sc, idx, vals, newid, K2, K3);
    pool_readout<<<BATCH, 512, 0, stream>>>(h, idx, vals, nullptr, z, K2, K3);

    // ---------- MLP head ----------
    mlp_head<<<BATCH, 256, 0, stream>>>(z, W1, bl1, W2, bl2, W3, bl3, (float*)d_out);
}

// Round 5
// 604.087 us; speedup vs baseline: 1.4727x; 1.2334x over previous
//
#include <hip/hip_runtime.h>
#include <math.h>

// Problem constants
#define BATCH 128
#define NPER 400
#define EPG 6400
#define NEDGE 819200
#define F_IN 400
#define HD 128
#define K1 320
#define K2 256
#define K3 205

typedef __bf16 bf16x8 __attribute__((ext_vector_type(8)));
typedef float f32x4 __attribute__((ext_vector_type(4)));

__device__ __forceinline__ unsigned short f2bf(float f) {
    unsigned u = __builtin_bit_cast(unsigned, f);
    unsigned r = u + 0x7fffu + ((u >> 16) & 1u);
    return (unsigned short)(r >> 16);
}
__device__ __forceinline__ float bf2f(unsigned short s) {
    unsigned u = ((unsigned)s) << 16;
    return __builtin_bit_cast(float, u);
}

// ---------------- workspace layout ----------------
static constexpr size_t SZ_TREL = 51200ull * 128 * 4;
static constexpr size_t OFF_TREL = 0;
static constexpr size_t OFF_H    = OFF_TREL + SZ_TREL;
static constexpr size_t OFF_HP   = OFF_H + SZ_TREL;
static constexpr size_t OFF_SC   = OFF_HP + 40960ull * 128 * 4;
static constexpr size_t OFF_IDX  = OFF_SC + 51200ull * 4;
static constexpr size_t OFF_VALS = OFF_IDX + 40960ull * 4;
static constexpr size_t OFF_NEWID= OFF_VALS + 40960ull * 4;
static constexpr size_t OFF_ES   = OFF_NEWID + 51200ull * 4;
static constexpr size_t OFF_ED   = OFF_ES + (size_t)NEDGE * 4;
static constexpr size_t OFF_EM   = OFF_ED + (size_t)NEDGE * 4;
static constexpr size_t OFF_Z    = OFF_EM + (size_t)NEDGE * 4;
static constexpr size_t OFF_COFF = OFF_Z + 128ull * 256 * 4;
static constexpr size_t OFF_CDEG = OFF_COFF + 51200ull * 4;
static constexpr size_t OFF_CSRC = OFF_CDEG + 51200ull * 4;
static constexpr size_t OFF_W1H  = OFF_CSRC + (size_t)NEDGE * 4;
static constexpr size_t OFF_W1L  = OFF_W1H + 256ull * 416 * 2;
static constexpr size_t OFF_W2H  = OFF_W1L + 256ull * 416 * 2;
static constexpr size_t OFF_W2L  = OFF_W2H + 256ull * 128 * 2;
static constexpr size_t OFF_W3H  = OFF_W2L + 256ull * 128 * 2;
static constexpr size_t OFF_W3L  = OFF_W3H + 256ull * 128 * 2;

// ---------------- weight split prep ----------------
// wt[n][k] (k padded to Kpad with zeros): n<128 -> Wrel[n][k], else Wroot[n-128][k]
// Split into bf16 hi/lo planes. grid dim3(ceil(Kpad/256), 256).
__global__ __launch_bounds__(256) void prep_w(const float* __restrict__ Wrel,
                                              const float* __restrict__ Wroot,
                                              unsigned short* __restrict__ wh,
                                              unsigned short* __restrict__ wl,
                                              int Kd, int Kpad) {
    int k = blockIdx.x * 256 + threadIdx.x;
    int n = blockIdx.y;
    if (k >= Kpad) return;
    float v = 0.f;
    if (k < Kd) v = (n < 128) ? Wrel[n * Kd + k] : Wroot[(n - 128) * Kd + k];
    unsigned short hi = f2bf(v);
    unsigned short lo = f2bf(v - bf2f(hi));
    wh[(size_t)n * Kpad + k] = hi;
    wl[(size_t)n * Kpad + k] = lo;
}

// ---------------- MFMA GEMM (bf16x3 split): [t_rel | h] = A @ W^T ----------
// A fp32 [M][Kd] (split to bf16 hi/lo in-register during staging).
// wh/wl: [256][Kpad] bf16 planes of W (rel|root stacked in n).
// Block: 256 thr (4 waves), tile 128(M) x 128(N); wave tile 64x64 via 4x4
// frags of 16x16x32 MFMA. grid = dim3(M/128, 2); blockIdx.y picks rel/root.
// LDS rows padded to 40 shorts (80 B = 20 banks -> conflict-free frag reads).
__global__ __launch_bounds__(256) void gemm_mfma(
    const float* __restrict__ A, const unsigned short* __restrict__ wh,
    const unsigned short* __restrict__ wl,
    float* __restrict__ t_rel, float* __restrict__ h,
    int Kd, int Kpad, int Ksteps) {
    __shared__ unsigned short S[20480];          // A:[2][128][40] + B:[2][128][40]
    unsigned short* Al = S;
    unsigned short* Bl = S + 10240;
    const int tid = threadIdx.x;
    const int m0 = blockIdx.x * 128;
    const int n0 = blockIdx.y * 128;
    const int wid = tid >> 6;
    const int lane = tid & 63;
    const int lm = lane & 15;
    const int qd = lane >> 4;
    const int wm0 = (wid >> 1) * 64;
    const int wn0 = (wid & 1) * 64;
    const int sr = tid >> 1;                     // staging row 0..127
    const int shf = tid & 1;                     // staging half (16 elems)

    f32x4 acc[4][4];
#pragma unroll
    for (int i = 0; i < 4; i++)
#pragma unroll
        for (int j = 0; j < 4; j++) acc[i][j] = (f32x4){0.f, 0.f, 0.f, 0.f};

    const float* Ab = A + (size_t)(m0 + sr) * Kd + shf * 16;
    const unsigned short* Bh = wh + (size_t)(n0 + sr) * Kpad + shf * 16;
    const unsigned short* Bo = wl + (size_t)(n0 + sr) * Kpad + shf * 16;
    unsigned short* Aw = &Al[sr * 40 + shf * 16];
    unsigned short* Bw = &Bl[sr * 40 + shf * 16];

    for (int s = 0; s < Ksteps; s++) {
        const int k0 = s * 32;
        // ---- load globals into regs ----
        float fv[16];
        if (k0 + shf * 16 < Kd) {
            *(float4*)&fv[0]  = *(const float4*)&Ab[k0];
            *(float4*)&fv[4]  = *(const float4*)&Ab[k0 + 4];
            *(float4*)&fv[8]  = *(const float4*)&Ab[k0 + 8];
            *(float4*)&fv[12] = *(const float4*)&Ab[k0 + 12];
        } else {
#pragma unroll
            for (int i = 0; i < 16; i++) fv[i] = 0.f;
        }
        uint4 bh0 = *(const uint4*)&Bh[k0];
        uint4 bh1 = *(const uint4*)&Bh[k0 + 8];
        uint4 bl0 = *(const uint4*)&Bo[k0];
        uint4 bl1 = *(const uint4*)&Bo[k0 + 8];
        // ---- split A in-register ----
        __align__(16) unsigned short hv[16], lv[16];
#pragma unroll
        for (int i = 0; i < 16; i++) {
            hv[i] = f2bf(fv[i]);
            lv[i] = f2bf(fv[i] - bf2f(hv[i]));
        }
        __syncthreads();     // previous tile fully consumed
        *(uint4*)&Aw[0]        = *(uint4*)&hv[0];
        *(uint4*)&Aw[8]        = *(uint4*)&hv[8];
        *(uint4*)&Aw[5120]     = *(uint4*)&lv[0];
        *(uint4*)&Aw[5120 + 8] = *(uint4*)&lv[8];
        *(uint4*)&Bw[0]        = bh0;
        *(uint4*)&Bw[8]        = bh1;
        *(uint4*)&Bw[5120]     = bl0;
        *(uint4*)&Bw[5120 + 8] = bl1;
        __syncthreads();     // staging visible
        // ---- fragments + MFMA ----
        bf16x8 ah[4], al[4], bhf[4], blf[4];
#pragma unroll
        for (int i = 0; i < 4; i++) {
            int ar = (wm0 + i * 16 + lm) * 40 + qd * 8;
            ah[i] = *(const bf16x8*)&Al[ar];
            al[i] = *(const bf16x8*)&Al[ar + 5120];
            int br = (wn0 + i * 16 + lm) * 40 + qd * 8;
            bhf[i] = *(const bf16x8*)&Bl[br];
            blf[i] = *(const bf16x8*)&Bl[br + 5120];
        }
#pragma unroll
        for (int i = 0; i < 4; i++)
#pragma unroll
            for (int j = 0; j < 4; j++) {
                acc[i][j] = __builtin_amdgcn_mfma_f32_16x16x32_bf16(
                    ah[i], bhf[j], acc[i][j], 0, 0, 0);
                acc[i][j] = __builtin_amdgcn_mfma_f32_16x16x32_bf16(
                    ah[i], blf[j], acc[i][j], 0, 0, 0);
                acc[i][j] = __builtin_amdgcn_mfma_f32_16x16x32_bf16(
                    al[i], bhf[j], acc[i][j], 0, 0, 0);
            }
    }
    // ---- epilogue: C/D layout col=lane&15, row=qd*4+reg ----
    float* out = (blockIdx.y == 0) ? t_rel : h;
#pragma unroll
    for (int i = 0; i < 4; i++)
#pragma unroll
        for (int j = 0; j < 4; j++) {
            int row = m0 + wm0 + i * 16 + qd * 4;
            int col = wn0 + j * 16 + lm;
#pragma unroll
            for (int r = 0; r < 4; r++)
                out[(size_t)(row + r) * 128 + col] = acc[i][j][r];
        }
}

// ---------------- CSR build for layer 1 (original edges, no mask) ----------
__global__ __launch_bounds__(1024) void csr_build0(
    const int* __restrict__ gsrc, const int* __restrict__ gdst,
    int* __restrict__ csr_off, int* __restrict__ csr_deg, int* __restrict__ csr_src) {
    __shared__ int cnt[NPER];
    __shared__ int cur[NPER];
    __shared__ int sscan[512];
    const int g = blockIdx.x;
    const int t = threadIdx.x;
    for (int i = t; i < NPER; i += 1024) cnt[i] = 0;
    __syncthreads();
    for (int e = t; e < EPG; e += 1024) {
        int dl = gdst[g * EPG + e] - g * NPER;
        atomicAdd(&cnt[dl], 1);
    }
    __syncthreads();
    if (t < 512) sscan[t] = (t < NPER) ? cnt[t] : 0;
    __syncthreads();
    for (int d = 1; d < 512; d <<= 1) {
        int v = 0;
        if (t < 512 && t >= d) v = sscan[t - d];
        __syncthreads();
        if (t < 512 && t >= d) sscan[t] += v;
        __syncthreads();
    }
    if (t < NPER) {
        int excl = (t == 0) ? 0 : sscan[t - 1];
        int st = g * EPG + excl;
        csr_off[g * NPER + t] = st;
        csr_deg[g * NPER + t] = cnt[t];
        cur[t] = st;
    }
    __syncthreads();
    for (int e = t; e < EPG; e += 1024) {
        int eg = g * EPG + e;
        int dl = gdst[eg] - g * NPER;
        int slot = atomicAdd(&cur[dl], 1);
        csr_src[slot] = gsrc[eg];
    }
}

// ---------------- fused edge remap + CSR build (layers 2,3 conv prep) -------
__global__ __launch_bounds__(1024) void csr_remap(
    const int* __restrict__ es_in, const int* __restrict__ ed_in,
    const int* __restrict__ em_in,
    const int* __restrict__ gsrc, const int* __restrict__ gdst,
    const int* __restrict__ newid,
    int* __restrict__ es_out, int* __restrict__ ed_out, int* __restrict__ em_out,
    int* __restrict__ csr_off, int* __restrict__ csr_deg, int* __restrict__ csr_src,
    int npg_prev, int k, int first) {
    __shared__ int nid[NPER];
    __shared__ int packed[EPG];
    __shared__ int cnt[K1];
    __shared__ int cur[K1];
    __shared__ int sscan[512];
    const int g = blockIdx.x;
    const int t = threadIdx.x;
    for (int i = t; i < npg_prev; i += 1024) nid[i] = newid[g * npg_prev + i];
    for (int i = t; i < k; i += 1024) cnt[i] = 0;
    __syncthreads();
    for (int e = t; e < EPG; e += 1024) {
        int eg = g * EPG + e;
        int sl, dl, m;
        if (first) { sl = gsrc[eg] - g * NPER; dl = gdst[eg] - g * NPER; m = 1; }
        else       { sl = es_in[eg]; dl = ed_in[eg]; m = em_in[eg]; }
        int ns = nid[sl], nd = nid[dl];
        int keep = (m && ns >= 0 && nd >= 0) ? 1 : 0;
        es_out[eg] = keep ? ns : 0;
        ed_out[eg] = keep ? nd : 0;
        em_out[eg] = keep;
        packed[e] = keep ? (ns | (nd << 16)) : -1;
        if (keep) atomicAdd(&cnt[nd], 1);
    }
    __syncthreads();
    if (t < 512) sscan[t] = (t < k) ? cnt[t] : 0;
    __syncthreads();
    for (int d = 1; d < 512; d <<= 1) {
        int v = 0;
        if (t < 512 && t >= d) v = sscan[t - d];
        __syncthreads();
        if (t < 512 && t >= d) sscan[t] += v;
        __syncthreads();
    }
    if (t < k) {
        int excl = (t == 0) ? 0 : sscan[t - 1];
        int st = g * EPG + excl;
        csr_off[g * k + t] = st;
        csr_deg[g * k + t] = cnt[t];
        cur[t] = st;
    }
    __syncthreads();
    for (int e = t; e < EPG; e += 1024) {
        int p = packed[e];
        if (p >= 0) {
            int ns = p & 0xffff, nd = p >> 16;
            int slot = atomicAdd(&cur[nd], 1);
            csr_src[slot] = g * k + ns;
        }
    }
}

// ---------------- Aggregation (gather) + combine + relu + score ------------
__global__ __launch_bounds__(256) void agg_score(
    const float* __restrict__ t_rel,
    const int* __restrict__ csr_off, const int* __restrict__ csr_deg,
    const int* __restrict__ csr_src,
    const float* __restrict__ bias, const float* __restrict__ pw,
    float* __restrict__ h, float* __restrict__ sc, int total_nodes) {
    const int wid = (blockIdx.x * 256 + threadIdx.x) >> 6;
    const int lane = threadIdx.x & 63;
    if (wid >= total_nodes) return;
    const int start = csr_off[wid];
    const int deg = csr_deg[wid];
    float a0 = 0.f, a1 = 0.f;
    for (int e = 0; e < deg; e++) {
        int srow = csr_src[start + e];
        float2 v = *(const float2*)&t_rel[(size_t)srow * 128 + lane * 2];
        a0 += v.x; a1 += v.y;
    }
    float2 bb = *(const float2*)&bias[lane * 2];
    size_t o = (size_t)wid * 128 + lane * 2;
    float2 hv = *(const float2*)&h[o];
    hv.x = fmaxf(hv.x + a0 + bb.x, 0.f);
    hv.y = fmaxf(hv.y + a1 + bb.y, 0.f);
    *(float2*)&h[o] = hv;
    float2 pp = *(const float2*)&pw[lane * 2];
    float d = hv.x * pp.x + hv.y * pp.y;
    float nr = pp.x * pp.x + pp.y * pp.y;
#pragma unroll
    for (int off = 32; off; off >>= 1) {
        d += __shfl_down(d, off, 64);
        nr += __shfl_down(nr, off, 64);
    }
    if (lane == 0) sc[wid] = d / (sqrtf(nr) + 1e-16f);
}

// ---------------- topk per graph: exact bitonic sort of 512 ----------------
__device__ __forceinline__ bool rank_before(float as, int ai, float bs, int bi) {
    return (as > bs) || (as == bs && ai < bi);
}
__global__ __launch_bounds__(256) void topk_kernel(const float* __restrict__ sc,
                                                   int* __restrict__ idxo,
                                                   float* __restrict__ valso,
                                                   int* __restrict__ newid,
                                                   int npg, int k) {
    __shared__ float sk[512];
    __shared__ int si[512];
    const int g = blockIdx.x;
    for (int t = threadIdx.x; t < 512; t += 256) {
        sk[t] = (t < npg) ? sc[g * npg + t] : -INFINITY;
        si[t] = t;
    }
    __syncthreads();
    for (int size = 2; size <= 512; size <<= 1) {
        for (int stride = size >> 1; stride; stride >>= 1) {
            for (int i = threadIdx.x; i < 512; i += 256) {
                int j = i ^ stride;
                if (j > i) {
                    bool up = ((i & size) == 0);
                    float a = sk[i], b = sk[j];
                    int ai = si[i], bi = si[j];
                    bool doswap = up ? rank_before(b, bi, a, ai)
                                     : rank_before(a, ai, b, bi);
                    if (doswap) { sk[i] = b; sk[j] = a; si[i] = bi; si[j] = ai; }
                }
            }
            __syncthreads();
        }
    }
    for (int t = threadIdx.x; t < 512; t += 256) {
        if (t < npg) {
            int orig = si[t];
            newid[g * npg + orig] = (t < k) ? t : -1;
            if (t < k) { idxo[g * k + t] = orig; valso[g * k + t] = sk[t]; }
        }
    }
}

// ---------------- fused gather+gate+(hp write)+readout ----------------
__global__ __launch_bounds__(512) void pool_readout(
    const float* __restrict__ h, const int* __restrict__ idx,
    const float* __restrict__ vals, float* __restrict__ hp,
    float* __restrict__ z, int npg, int k) {
    __shared__ float tg[K1];
    __shared__ int ix[K1];
    __shared__ float pmx[4][128], psm[4][128];
    const int g = blockIdx.x;
    const int f = threadIdx.x & 127;
    const int jq = threadIdx.x >> 7;
    for (int j = threadIdx.x; j < k; j += 512) {
        tg[j] = tanhf(vals[g * k + j]);
        ix[j] = idx[g * k + j];
    }
    __syncthreads();
    float mx = -INFINITY, sm = 0.f;
    for (int j = jq; j < k; j += 4) {
        float v = h[(size_t)(g * npg + ix[j]) * 128 + f] * tg[j];
        if (hp) hp[(size_t)(g * k + j) * 128 + f] = v;
        mx = fmaxf(mx, v);
        sm += v;
    }
    pmx[jq][f] = mx; psm[jq][f] = sm;
    __syncthreads();
    if (threadIdx.x < 128) {
        mx = fmaxf(fmaxf(pmx[0][f], pmx[1][f]), fmaxf(pmx[2][f], pmx[3][f]));
        sm = psm[0][f] + psm[1][f] + psm[2][f] + psm[3][f];
        z[g * 256 + f] += mx;
        z[g * 256 + 128 + f] += sm / (float)k;
    }
}

// ---------------- MLP head + log_softmax ----------------
__global__ __launch_bounds__(256) void mlp_head(const float* __restrict__ z,
                                                const float* __restrict__ W1,
                                                const float* __restrict__ bl1,
                                                const float* __restrict__ W2,
                                                const float* __restrict__ bl2,
                                                const float* __restrict__ W3,
                                                const float* __restrict__ bl3,
                                                float* __restrict__ out) {
    __shared__ float zs[256], l1[128], l2[64];
    const int g = blockIdx.x, t = threadIdx.x;
    zs[t] = z[g * 256 + t];
    __syncthreads();
    if (t < 128) {
        float s = bl1[t];
        const float* w = &W1[t * 256];
        for (int i = 0; i < 256; i++) s += w[i] * zs[i];
        l1[t] = fmaxf(s, 0.f);
    }
    __syncthreads();
    if (t < 64) {
        float s = bl2[t];
        const float* w = &W2[t * 128];
        for (int i = 0; i < 128; i++) s += w[i] * l1[i];
        l2[t] = fmaxf(s, 0.f);
    }
    __syncthreads();
    if (t == 0) {
        float a = bl3[0], b = bl3[1];
        for (int i = 0; i < 64; i++) { a += W3[i] * l2[i]; b += W3[64 + i] * l2[i]; }
        float m = fmaxf(a, b);
        float lse = m + logf(expf(a - m) + expf(b - m));
        out[g * 2 + 0] = a - lse;
        out[g * 2 + 1] = b - lse;
    }
}

// ---------------- launch ----------------
extern "C" void kernel_launch(void* const* d_in, const int* in_sizes, int n_in,
                              void* d_out, int out_size, void* d_ws, size_t ws_size,
                              hipStream_t stream) {
    const float* x        = (const float*)d_in[0];
    const int*   edge_src = (const int*)d_in[1];
    const int*   edge_dst = (const int*)d_in[2];
    const float* Wrel1 = (const float*)d_in[4];
    const float* Wroot1= (const float*)d_in[5];
    const float* b1    = (const float*)d_in[6];
    const float* pw1   = (const float*)d_in[7];
    const float* Wrel2 = (const float*)d_in[8];
    const float* Wroot2= (const float*)d_in[9];
    const float* b2    = (const float*)d_in[10];
    const float* pw2   = (const float*)d_in[11];
    const float* Wrel3 = (const float*)d_in[12];
    const float* Wroot3= (const float*)d_in[13];
    const float* b3    = (const float*)d_in[14];
    const float* pw3   = (const float*)d_in[15];
    const float* W1    = (const float*)d_in[16];
    const float* bl1   = (const float*)d_in[17];
    const float* W2    = (const float*)d_in[18];
    const float* bl2   = (const float*)d_in[19];
    const float* W3    = (const float*)d_in[20];
    const float* bl3   = (const float*)d_in[21];

    char* ws = (char*)d_ws;
    float* t_rel = (float*)(ws + OFF_TREL);
    float* h     = (float*)(ws + OFF_H);
    float* hp    = (float*)(ws + OFF_HP);
    float* sc    = (float*)(ws + OFF_SC);
    int*   idx   = (int*)(ws + OFF_IDX);
    float* vals  = (float*)(ws + OFF_VALS);
    int*   newid = (int*)(ws + OFF_NEWID);
    int*   es    = (int*)(ws + OFF_ES);
    int*   ed    = (int*)(ws + OFF_ED);
    int*   em    = (int*)(ws + OFF_EM);
    float* z     = (float*)(ws + OFF_Z);
    int*   coff  = (int*)(ws + OFF_COFF);
    int*   cdeg  = (int*)(ws + OFF_CDEG);
    int*   csrc  = (int*)(ws + OFF_CSRC);
    unsigned short* w1h = (unsigned short*)(ws + OFF_W1H);
    unsigned short* w1l = (unsigned short*)(ws + OFF_W1L);
    unsigned short* w2h = (unsigned short*)(ws + OFF_W2H);
    unsigned short* w2l = (unsigned short*)(ws + OFF_W2L);
    unsigned short* w3h = (unsigned short*)(ws + OFF_W3H);
    unsigned short* w3l = (unsigned short*)(ws + OFF_W3L);

    hipMemsetAsync(z, 0, 128ull * 256 * 4, stream);
    prep_w<<<dim3(2, 256), 256, 0, stream>>>(Wrel1, Wroot1, w1h, w1l, F_IN, 416);
    prep_w<<<dim3(1, 256), 256, 0, stream>>>(Wrel2, Wroot2, w2h, w2l, HD, 128);
    prep_w<<<dim3(1, 256), 256, 0, stream>>>(Wrel3, Wroot3, w3h, w3l, HD, 128);
    csr_build0<<<BATCH, 1024, 0, stream>>>(edge_src, edge_dst, coff, cdeg, csrc);

    // ---------- layer 1 ----------
    gemm_mfma<<<dim3(400, 2), 256, 0, stream>>>(x, w1h, w1l, t_rel, h, F_IN, 416, 13);
    agg_score<<<51200 / 4, 256, 0, stream>>>(t_rel, coff, cdeg, csrc, b1, pw1,
                                             h, sc, 51200);
    topk_kernel<<<BATCH, 256, 0, stream>>>(sc, idx, vals, newid, NPER, K1);
    csr_remap<<<BATCH, 1024, 0, stream>>>(nullptr, nullptr, nullptr,
                                          edge_src, edge_dst, newid,
                                          es, ed, em, coff, cdeg, csrc,
                                          NPER, K1, 1);
    pool_readout<<<BATCH, 512, 0, stream>>>(h, idx, vals, hp, z, NPER, K1);

    // ---------- layer 2 ----------
    gemm_mfma<<<dim3(320, 2), 256, 0, stream>>>(hp, w2h, w2l, t_rel, h, HD, 128, 4);
    agg_score<<<40960 / 4, 256, 0, stream>>>(t_rel, coff, cdeg, csrc, b2, pw2,
                                             h, sc, 40960);
    topk_kernel<<<BATCH, 256, 0, stream>>>(sc, idx, vals, newid, K1, K2);
    csr_remap<<<BATCH, 1024, 0, stream>>>(es, ed, em, nullptr, nullptr, newid,
                                          es, ed, em, coff, cdeg, csrc,
                                          K1, K2, 0);
    pool_readout<<<BATCH, 512, 0, stream>>>(h, idx, vals, hp, z, K1, K2);

    // ---------- layer 3 ----------
    gemm_mfma<<<dim3(256, 2), 256, 0, stream>>>(hp, w3h, w3l, t_rel, h, HD, 128, 4);
    agg_score<<<32768 / 4, 256, 0, stream>>>(t_rel, coff, cdeg, csrc, b3, pw3,
                                             h, sc, 32768);
    topk_kernel<<<BATCH, 256, 0, stream>>>(sc, idx, vals, newid, K2, K3);
    pool_readout<<<BATCH, 512, 0, stream>>>(h, idx, vals, nullptr, z, K2, K3);

    // ---------- MLP head ----------
    mlp_head<<<BATCH, 256, 0, stream>>>(z, W1, bl1, W2, bl2, W3, bl3, (float*)d_out);
}

// Round 6
// 518.233 us; speedup vs baseline: 1.7167x; 1.1657x over previous
//
#include <hip/hip_runtime.h>
#include <math.h>

// Problem constants
#define BATCH 128
#define NPER 400
#define EPG 6400
#define NEDGE 819200
#define F_IN 400
#define HD 128
#define K1 320
#define K2 256
#define K3 205

typedef __bf16 bf16x8 __attribute__((ext_vector_type(8)));
typedef float f32x4 __attribute__((ext_vector_type(4)));

__device__ __forceinline__ unsigned short f2bf(float f) {
    unsigned u = __builtin_bit_cast(unsigned, f);
    unsigned r = u + 0x7fffu + ((u >> 16) & 1u);
    return (unsigned short)(r >> 16);
}
__device__ __forceinline__ float bf2f(unsigned short s) {
    unsigned u = ((unsigned)s) << 16;
    return __builtin_bit_cast(float, u);
}

// ---------------- workspace layout ----------------
static constexpr size_t SZ_TREL = 51200ull * 128 * 4;
static constexpr size_t OFF_TREL = 0;
static constexpr size_t OFF_H    = OFF_TREL + SZ_TREL;
static constexpr size_t OFF_HP   = OFF_H + SZ_TREL;
static constexpr size_t OFF_SC   = OFF_HP + 40960ull * 128 * 4;
static constexpr size_t OFF_IDX  = OFF_SC + 51200ull * 4;
static constexpr size_t OFF_VALS = OFF_IDX + 40960ull * 4;
static constexpr size_t OFF_NEWID= OFF_VALS + 40960ull * 4;
static constexpr size_t OFF_ES   = OFF_NEWID + 51200ull * 4;
static constexpr size_t OFF_ED   = OFF_ES + (size_t)NEDGE * 4;
static constexpr size_t OFF_EM   = OFF_ED + (size_t)NEDGE * 4;
static constexpr size_t OFF_Z    = OFF_EM + (size_t)NEDGE * 4;
static constexpr size_t OFF_COFF = OFF_Z + 128ull * 256 * 4;
static constexpr size_t OFF_CDEG = OFF_COFF + 51200ull * 4;
static constexpr size_t OFF_CSRC = OFF_CDEG + 51200ull * 4;
static constexpr size_t OFF_W1H  = OFF_CSRC + (size_t)NEDGE * 4;
static constexpr size_t OFF_W1L  = OFF_W1H + 256ull * 416 * 2;
static constexpr size_t OFF_W2H  = OFF_W1L + 256ull * 416 * 2;
static constexpr size_t OFF_W2L  = OFF_W2H + 256ull * 128 * 2;
static constexpr size_t OFF_W3H  = OFF_W2L + 256ull * 128 * 2;
static constexpr size_t OFF_W3L  = OFF_W3H + 256ull * 128 * 2;

// ---------------- weight split prep ----------------
__global__ __launch_bounds__(256) void prep_w(const float* __restrict__ Wrel,
                                              const float* __restrict__ Wroot,
                                              unsigned short* __restrict__ wh,
                                              unsigned short* __restrict__ wl,
                                              int Kd, int Kpad) {
    int k = blockIdx.x * 256 + threadIdx.x;
    int n = blockIdx.y;
    if (k >= Kpad) return;
    float v = 0.f;
    if (k < Kd) v = (n < 128) ? Wrel[n * Kd + k] : Wroot[(n - 128) * Kd + k];
    unsigned short hi = f2bf(v);
    unsigned short lo = f2bf(v - bf2f(hi));
    wh[(size_t)n * Kpad + k] = hi;
    wl[(size_t)n * Kpad + k] = lo;
}

// ---------------- MFMA GEMM (bf16x3 split): [t_rel | h] = A @ W^T ----------
__global__ __launch_bounds__(256) void gemm_mfma(
    const float* __restrict__ A, const unsigned short* __restrict__ wh,
    const unsigned short* __restrict__ wl,
    float* __restrict__ t_rel, float* __restrict__ h,
    int Kd, int Kpad, int Ksteps) {
    __shared__ unsigned short S[20480];          // A:[2][128][40] + B:[2][128][40]
    unsigned short* Al = S;
    unsigned short* Bl = S + 10240;
    const int tid = threadIdx.x;
    const int m0 = blockIdx.x * 128;
    const int n0 = blockIdx.y * 128;
    const int wid = tid >> 6;
    const int lane = tid & 63;
    const int lm = lane & 15;
    const int qd = lane >> 4;
    const int wm0 = (wid >> 1) * 64;
    const int wn0 = (wid & 1) * 64;
    const int sr = tid >> 1;
    const int shf = tid & 1;

    f32x4 acc[4][4];
#pragma unroll
    for (int i = 0; i < 4; i++)
#pragma unroll
        for (int j = 0; j < 4; j++) acc[i][j] = (f32x4){0.f, 0.f, 0.f, 0.f};

    const float* Ab = A + (size_t)(m0 + sr) * Kd + shf * 16;
    const unsigned short* Bh = wh + (size_t)(n0 + sr) * Kpad + shf * 16;
    const unsigned short* Bo = wl + (size_t)(n0 + sr) * Kpad + shf * 16;
    unsigned short* Aw = &Al[sr * 40 + shf * 16];
    unsigned short* Bw = &Bl[sr * 40 + shf * 16];

    for (int s = 0; s < Ksteps; s++) {
        const int k0 = s * 32;
        float fv[16];
        if (k0 + shf * 16 < Kd) {
            *(float4*)&fv[0]  = *(const float4*)&Ab[k0];
            *(float4*)&fv[4]  = *(const float4*)&Ab[k0 + 4];
            *(float4*)&fv[8]  = *(const float4*)&Ab[k0 + 8];
            *(float4*)&fv[12] = *(const float4*)&Ab[k0 + 12];
        } else {
#pragma unroll
            for (int i = 0; i < 16; i++) fv[i] = 0.f;
        }
        uint4 bh0 = *(const uint4*)&Bh[k0];
        uint4 bh1 = *(const uint4*)&Bh[k0 + 8];
        uint4 bl0 = *(const uint4*)&Bo[k0];
        uint4 bl1 = *(const uint4*)&Bo[k0 + 8];
        __align__(16) unsigned short hv[16], lv[16];
#pragma unroll
        for (int i = 0; i < 16; i++) {
            hv[i] = f2bf(fv[i]);
            lv[i] = f2bf(fv[i] - bf2f(hv[i]));
        }
        __syncthreads();
        *(uint4*)&Aw[0]        = *(uint4*)&hv[0];
        *(uint4*)&Aw[8]        = *(uint4*)&hv[8];
        *(uint4*)&Aw[5120]     = *(uint4*)&lv[0];
        *(uint4*)&Aw[5120 + 8] = *(uint4*)&lv[8];
        *(uint4*)&Bw[0]        = bh0;
        *(uint4*)&Bw[8]        = bh1;
        *(uint4*)&Bw[5120]     = bl0;
        *(uint4*)&Bw[5120 + 8] = bl1;
        __syncthreads();
        bf16x8 ah[4], al[4], bhf[4], blf[4];
#pragma unroll
        for (int i = 0; i < 4; i++) {
            int ar = (wm0 + i * 16 + lm) * 40 + qd * 8;
            ah[i] = *(const bf16x8*)&Al[ar];
            al[i] = *(const bf16x8*)&Al[ar + 5120];
            int br = (wn0 + i * 16 + lm) * 40 + qd * 8;
            bhf[i] = *(const bf16x8*)&Bl[br];
            blf[i] = *(const bf16x8*)&Bl[br + 5120];
        }
#pragma unroll
        for (int i = 0; i < 4; i++)
#pragma unroll
            for (int j = 0; j < 4; j++) {
                acc[i][j] = __builtin_amdgcn_mfma_f32_16x16x32_bf16(
                    ah[i], bhf[j], acc[i][j], 0, 0, 0);
                acc[i][j] = __builtin_amdgcn_mfma_f32_16x16x32_bf16(
                    ah[i], blf[j], acc[i][j], 0, 0, 0);
                acc[i][j] = __builtin_amdgcn_mfma_f32_16x16x32_bf16(
                    al[i], bhf[j], acc[i][j], 0, 0, 0);
            }
    }
    float* out = (blockIdx.y == 0) ? t_rel : h;
#pragma unroll
    for (int i = 0; i < 4; i++)
#pragma unroll
        for (int j = 0; j < 4; j++) {
            int row = m0 + wm0 + i * 16 + qd * 4;
            int col = wn0 + j * 16 + lm;
#pragma unroll
            for (int r = 0; r < 4; r++)
                out[(size_t)(row + r) * 128 + col] = acc[i][j][r];
        }
}

// ---------------- CSR build for layer 1 (original edges, no mask) ----------
__global__ __launch_bounds__(1024) void csr_build0(
    const int* __restrict__ gsrc, const int* __restrict__ gdst,
    int* __restrict__ csr_off, int* __restrict__ csr_deg, int* __restrict__ csr_src) {
    __shared__ int cnt[NPER];
    __shared__ int cur[NPER];
    __shared__ int sscan[512];
    const int g = blockIdx.x;
    const int t = threadIdx.x;
    for (int i = t; i < NPER; i += 1024) cnt[i] = 0;
    __syncthreads();
    for (int e = t; e < EPG; e += 1024) {
        int dl = gdst[g * EPG + e] - g * NPER;
        atomicAdd(&cnt[dl], 1);
    }
    __syncthreads();
    if (t < 512) sscan[t] = (t < NPER) ? cnt[t] : 0;
    __syncthreads();
    for (int d = 1; d < 512; d <<= 1) {
        int v = 0;
        if (t < 512 && t >= d) v = sscan[t - d];
        __syncthreads();
        if (t < 512 && t >= d) sscan[t] += v;
        __syncthreads();
    }
    if (t < NPER) {
        int excl = (t == 0) ? 0 : sscan[t - 1];
        int st = g * EPG + excl;
        csr_off[g * NPER + t] = st;
        csr_deg[g * NPER + t] = cnt[t];
        cur[t] = st;
    }
    __syncthreads();
    for (int e = t; e < EPG; e += 1024) {
        int eg = g * EPG + e;
        int dl = gdst[eg] - g * NPER;
        int slot = atomicAdd(&cur[dl], 1);
        csr_src[slot] = gsrc[eg];
    }
}

// ---------------- fused edge remap + CSR build (layers 2,3 conv prep) -------
__global__ __launch_bounds__(1024) void csr_remap(
    const int* __restrict__ es_in, const int* __restrict__ ed_in,
    const int* __restrict__ em_in,
    const int* __restrict__ gsrc, const int* __restrict__ gdst,
    const int* __restrict__ newid,
    int* __restrict__ es_out, int* __restrict__ ed_out, int* __restrict__ em_out,
    int* __restrict__ csr_off, int* __restrict__ csr_deg, int* __restrict__ csr_src,
    int npg_prev, int k, int first) {
    __shared__ int nid[NPER];
    __shared__ int packed[EPG];
    __shared__ int cnt[K1];
    __shared__ int cur[K1];
    __shared__ int sscan[512];
    const int g = blockIdx.x;
    const int t = threadIdx.x;
    for (int i = t; i < npg_prev; i += 1024) nid[i] = newid[g * npg_prev + i];
    for (int i = t; i < k; i += 1024) cnt[i] = 0;
    __syncthreads();
    for (int e = t; e < EPG; e += 1024) {
        int eg = g * EPG + e;
        int sl, dl, m;
        if (first) { sl = gsrc[eg] - g * NPER; dl = gdst[eg] - g * NPER; m = 1; }
        else       { sl = es_in[eg]; dl = ed_in[eg]; m = em_in[eg]; }
        int ns = nid[sl], nd = nid[dl];
        int keep = (m && ns >= 0 && nd >= 0) ? 1 : 0;
        es_out[eg] = keep ? ns : 0;
        ed_out[eg] = keep ? nd : 0;
        em_out[eg] = keep;
        packed[e] = keep ? (ns | (nd << 16)) : -1;
        if (keep) atomicAdd(&cnt[nd], 1);
    }
    __syncthreads();
    if (t < 512) sscan[t] = (t < k) ? cnt[t] : 0;
    __syncthreads();
    for (int d = 1; d < 512; d <<= 1) {
        int v = 0;
        if (t < 512 && t >= d) v = sscan[t - d];
        __syncthreads();
        if (t < 512 && t >= d) sscan[t] += v;
        __syncthreads();
    }
    if (t < k) {
        int excl = (t == 0) ? 0 : sscan[t - 1];
        int st = g * EPG + excl;
        csr_off[g * k + t] = st;
        csr_deg[g * k + t] = cnt[t];
        cur[t] = st;
    }
    __syncthreads();
    for (int e = t; e < EPG; e += 1024) {
        int p = packed[e];
        if (p >= 0) {
            int ns = p & 0xffff, nd = p >> 16;
            int slot = atomicAdd(&cur[nd], 1);
            csr_src[slot] = g * k + ns;
        }
    }
}

// ---------------- Aggregation (gather) + combine + relu + score ------------
// One wave per destination node. XCD-swizzled block->node mapping: blocks with
// the same (blockIdx&7) [same XCD under round-robin dispatch] cover one
// contiguous 16-graph slice so each XCD's L2 holds only its slice of t_rel.
// Gather loop unrolled x4 with independent accumulators for MLP.
__global__ __launch_bounds__(256) void agg_score(
    const float* __restrict__ t_rel,
    const int* __restrict__ csr_off, const int* __restrict__ csr_deg,
    const int* __restrict__ csr_src,
    const float* __restrict__ bias, const float* __restrict__ pw,
    float* __restrict__ h, float* __restrict__ sc, int npg) {
    const int bpx = (BATCH / 8) * (npg >> 2);   // blocks per XCD slice
    const int xcd = blockIdx.x & 7;
    const int j = blockIdx.x >> 3;              // 0..bpx-1
    const int bpg = npg >> 2;                   // blocks per graph
    const int graph = xcd * (BATCH / 8) + j / bpg;
    const int nblk = j - (j / bpg) * bpg;
    (void)bpx;
    const int wid = graph * npg + nblk * 4 + (threadIdx.x >> 6);
    const int lane = threadIdx.x & 63;

    const int start = csr_off[wid];
    const int deg = csr_deg[wid];
    const size_t fo = (size_t)lane * 2;
    float a0 = 0.f, a1 = 0.f, b0 = 0.f, b1 = 0.f;
    float c0 = 0.f, c1 = 0.f, d0 = 0.f, d1 = 0.f;
    int e = 0;
    for (; e + 4 <= deg; e += 4) {
        int s0 = csr_src[start + e];
        int s1 = csr_src[start + e + 1];
        int s2 = csr_src[start + e + 2];
        int s3 = csr_src[start + e + 3];
        float2 v0 = *(const float2*)&t_rel[(size_t)s0 * 128 + fo];
        float2 v1 = *(const float2*)&t_rel[(size_t)s1 * 128 + fo];
        float2 v2 = *(const float2*)&t_rel[(size_t)s2 * 128 + fo];
        float2 v3 = *(const float2*)&t_rel[(size_t)s3 * 128 + fo];
        a0 += v0.x; a1 += v0.y;
        b0 += v1.x; b1 += v1.y;
        c0 += v2.x; c1 += v2.y;
        d0 += v3.x; d1 += v3.y;
    }
    for (; e < deg; e++) {
        int s0 = csr_src[start + e];
        float2 v0 = *(const float2*)&t_rel[(size_t)s0 * 128 + fo];
        a0 += v0.x; a1 += v0.y;
    }
    a0 += b0 + c0 + d0;
    a1 += b1 + c1 + d1;

    float2 bb = *(const float2*)&bias[fo];
    size_t o = (size_t)wid * 128 + fo;
    float2 hv = *(const float2*)&h[o];
    hv.x = fmaxf(hv.x + a0 + bb.x, 0.f);
    hv.y = fmaxf(hv.y + a1 + bb.y, 0.f);
    *(float2*)&h[o] = hv;
    float2 pp = *(const float2*)&pw[fo];
    float d = hv.x * pp.x + hv.y * pp.y;
    float nr = pp.x * pp.x + pp.y * pp.y;
#pragma unroll
    for (int off = 32; off; off >>= 1) {
        d += __shfl_down(d, off, 64);
        nr += __shfl_down(nr, off, 64);
    }
    if (lane == 0) sc[wid] = d / (sqrtf(nr) + 1e-16f);
}

// ---------------- topk per graph: exact bitonic sort of 512 ----------------
__device__ __forceinline__ bool rank_before(float as, int ai, float bs, int bi) {
    return (as > bs) || (as == bs && ai < bi);
}
__global__ __launch_bounds__(256) void topk_kernel(const float* __restrict__ sc,
                                                   int* __restrict__ idxo,
                                                   float* __restrict__ valso,
                                                   int* __restrict__ newid,
                                                   int npg, int k) {
    __shared__ float sk[512];
    __shared__ int si[512];
    const int g = blockIdx.x;
    for (int t = threadIdx.x; t < 512; t += 256) {
        sk[t] = (t < npg) ? sc[g * npg + t] : -INFINITY;
        si[t] = t;
    }
    __syncthreads();
    for (int size = 2; size <= 512; size <<= 1) {
        for (int stride = size >> 1; stride; stride >>= 1) {
            for (int i = threadIdx.x; i < 512; i += 256) {
                int j = i ^ stride;
                if (j > i) {
                    bool up = ((i & size) == 0);
                    float a = sk[i], b = sk[j];
                    int ai = si[i], bi = si[j];
                    bool doswap = up ? rank_before(b, bi, a, ai)
                                     : rank_before(a, ai, b, bi);
                    if (doswap) { sk[i] = b; sk[j] = a; si[i] = bi; si[j] = ai; }
                }
            }
            __syncthreads();
        }
    }
    for (int t = threadIdx.x; t < 512; t += 256) {
        if (t < npg) {
            int orig = si[t];
            newid[g * npg + orig] = (t < k) ? t : -1;
            if (t < k) { idxo[g * k + t] = orig; valso[g * k + t] = sk[t]; }
        }
    }
}

// ---------------- fused gather+gate+(hp write)+readout ----------------
__global__ __launch_bounds__(512) void pool_readout(
    const float* __restrict__ h, const int* __restrict__ idx,
    const float* __restrict__ vals, float* __restrict__ hp,
    float* __restrict__ z, int npg, int k) {
    __shared__ float tg[K1];
    __shared__ int ix[K1];
    __shared__ float pmx[4][128], psm[4][128];
    const int g = blockIdx.x;
    const int f = threadIdx.x & 127;
    const int jq = threadIdx.x >> 7;
    for (int j = threadIdx.x; j < k; j += 512) {
        tg[j] = tanhf(vals[g * k + j]);
        ix[j] = idx[g * k + j];
    }
    __syncthreads();
    float mx = -INFINITY, sm = 0.f;
    for (int j = jq; j < k; j += 4) {
        float v = h[(size_t)(g * npg + ix[j]) * 128 + f] * tg[j];
        if (hp) hp[(size_t)(g * k + j) * 128 + f] = v;
        mx = fmaxf(mx, v);
        sm += v;
    }
    pmx[jq][f] = mx; psm[jq][f] = sm;
    __syncthreads();
    if (threadIdx.x < 128) {
        mx = fmaxf(fmaxf(pmx[0][f], pmx[1][f]), fmaxf(pmx[2][f], pmx[3][f]));
        sm = psm[0][f] + psm[1][f] + psm[2][f] + psm[3][f];
        z[g * 256 + f] += mx;
        z[g * 256 + 128 + f] += sm / (float)k;
    }
}

// ---------------- MLP head + log_softmax ----------------
__global__ __launch_bounds__(256) void mlp_head(const float* __restrict__ z,
                                                const float* __restrict__ W1,
                                                const float* __restrict__ bl1,
                                                const float* __restrict__ W2,
                                                const float* __restrict__ bl2,
                                                const float* __restrict__ W3,
                                                const float* __restrict__ bl3,
                                                float* __restrict__ out) {
    __shared__ float zs[256], l1[128], l2[64];
    const int g = blockIdx.x, t = threadIdx.x;
    zs[t] = z[g * 256 + t];
    __syncthreads();
    if (t < 128) {
        float s = bl1[t];
        const float* w = &W1[t * 256];
        for (int i = 0; i < 256; i++) s += w[i] * zs[i];
        l1[t] = fmaxf(s, 0.f);
    }
    __syncthreads();
    if (t < 64) {
        float s = bl2[t];
        const float* w = &W2[t * 128];
        for (int i = 0; i < 128; i++) s += w[i] * l1[i];
        l2[t] = fmaxf(s, 0.f);
    }
    __syncthreads();
    if (t == 0) {
        float a = bl3[0], b = bl3[1];
        for (int i = 0; i < 64; i++) { a += W3[i] * l2[i]; b += W3[64 + i] * l2[i]; }
        float m = fmaxf(a, b);
        float lse = m + logf(expf(a - m) + expf(b - m));
        out[g * 2 + 0] = a - lse;
        out[g * 2 + 1] = b - lse;
    }
}

// ---------------- launch ----------------
extern "C" void kernel_launch(void* const* d_in, const int* in_sizes, int n_in,
                              void* d_out, int out_size, void* d_ws, size_t ws_size,
                              hipStream_t stream) {
    const float* x        = (const float*)d_in[0];
    const int*   edge_src = (const int*)d_in[1];
    const int*   edge_dst = (const int*)d_in[2];
    const float* Wrel1 = (const float*)d_in[4];
    const float* Wroot1= (const float*)d_in[5];
    const float* b1    = (const float*)d_in[6];
    const float* pw1   = (const float*)d_in[7];
    const float* Wrel2 = (const float*)d_in[8];
    const float* Wroot2= (const float*)d_in[9];
    const float* b2    = (const float*)d_in[10];
    const float* pw2   = (const float*)d_in[11];
    const float* Wrel3 = (const float*)d_in[12];
    const float* Wroot3= (const float*)d_in[13];
    const float* b3    = (const float*)d_in[14];
    const float* pw3   = (const float*)d_in[15];
    const float* W1    = (const float*)d_in[16];
    const float* bl1   = (const float*)d_in[17];
    const float* W2    = (const float*)d_in[18];
    const float* bl2   = (const float*)d_in[19];
    const float* W3    = (const float*)d_in[20];
    const float* bl3   = (const float*)d_in[21];

    char* ws = (char*)d_ws;
    float* t_rel = (float*)(ws + OFF_TREL);
    float* h     = (float*)(ws + OFF_H);
    float* hp    = (float*)(ws + OFF_HP);
    float* sc    = (float*)(ws + OFF_SC);
    int*   idx   = (int*)(ws + OFF_IDX);
    float* vals  = (float*)(ws + OFF_VALS);
    int*   newid = (int*)(ws + OFF_NEWID);
    int*   es    = (int*)(ws + OFF_ES);
    int*   ed    = (int*)(ws + OFF_ED);
    int*   em    = (int*)(ws + OFF_EM);
    float* z     = (float*)(ws + OFF_Z);
    int*   coff  = (int*)(ws + OFF_COFF);
    int*   cdeg  = (int*)(ws + OFF_CDEG);
    int*   csrc  = (int*)(ws + OFF_CSRC);
    unsigned short* w1h = (unsigned short*)(ws + OFF_W1H);
    unsigned short* w1l = (unsigned short*)(ws + OFF_W1L);
    unsigned short* w2h = (unsigned short*)(ws + OFF_W2H);
    unsigned short* w2l = (unsigned short*)(ws + OFF_W2L);
    unsigned short* w3h = (unsigned short*)(ws + OFF_W3H);
    unsigned short* w3l = (unsigned short*)(ws + OFF_W3L);

    hipMemsetAsync(z, 0, 128ull * 256 * 4, stream);
    prep_w<<<dim3(2, 256), 256, 0, stream>>>(Wrel1, Wroot1, w1h, w1l, F_IN, 416);
    prep_w<<<dim3(1, 256), 256, 0, stream>>>(Wrel2, Wroot2, w2h, w2l, HD, 128);
    prep_w<<<dim3(1, 256), 256, 0, stream>>>(Wrel3, Wroot3, w3h, w3l, HD, 128);
    csr_build0<<<BATCH, 1024, 0, stream>>>(edge_src, edge_dst, coff, cdeg, csrc);

    // ---------- layer 1 ----------
    gemm_mfma<<<dim3(400, 2), 256, 0, stream>>>(x, w1h, w1l, t_rel, h, F_IN, 416, 13);
    agg_score<<<51200 / 4, 256, 0, stream>>>(t_rel, coff, cdeg, csrc, b1, pw1,
                                             h, sc, NPER);
    topk_kernel<<<BATCH, 256, 0, stream>>>(sc, idx, vals, newid, NPER, K1);
    csr_remap<<<BATCH, 1024, 0, stream>>>(nullptr, nullptr, nullptr,
                                          edge_src, edge_dst, newid,
                                          es, ed, em, coff, cdeg, csrc,
                                          NPER, K1, 1);
    pool_readout<<<BATCH, 512, 0, stream>>>(h, idx, vals, hp, z, NPER, K1);

    // ---------- layer 2 ----------
    gemm_mfma<<<dim3(320, 2), 256, 0, stream>>>(hp, w2h, w2l, t_rel, h, HD, 128, 4);
    agg_score<<<40960 / 4, 256, 0, stream>>>(t_rel, coff, cdeg, csrc, b2, pw2,
                                             h, sc, K1);
    topk_kernel<<<BATCH, 256, 0, stream>>>(sc, idx, vals, newid, K1, K2);
    csr_remap<<<BATCH, 1024, 0, stream>>>(es, ed, em, nullptr, nullptr, newid,
                                          es, ed, em, coff, cdeg, csrc,
                                          K1, K2, 0);
    pool_readout<<<BATCH, 512, 0, stream>>>(h, idx, vals, hp, z, K1, K2);

    // ---------- layer 3 ----------
    gemm_mfma<<<dim3(256, 2), 256, 0, stream>>>(hp, w3h, w3l, t_rel, h, HD, 128, 4);
    agg_score<<<32768 / 4, 256, 0, stream>>>(t_rel, coff, cdeg, csrc, b3, pw3,
                                             h, sc, K2);
    topk_kernel<<<BATCH, 256, 0, stream>>>(sc, idx, vals, newid, K2, K3);
    pool_readout<<<BATCH, 512, 0, stream>>>(h, idx, vals, nullptr, z, K2, K3);

    // ---------- MLP head ----------
    mlp_head<<<BATCH, 256, 0, stream>>>(z, W1, bl1, W2, bl2, W3, bl3, (float*)d_out);
}